// Round 3
// baseline (844.837 us; speedup 1.0000x reference)
//
#include <hip/hip_runtime.h>

#define DM 128
#define NH 8
#define DH 16

typedef __bf16 bf8 __attribute__((ext_vector_type(8)));
typedef float  f4  __attribute__((ext_vector_type(4)));

__device__ __forceinline__ f4 mfma16(bf8 a, bf8 b, f4 c){
  return __builtin_amdgcn_mfma_f32_16x16x32_bf16(a, b, c, 0, 0, 0);
}

// convert 8 contiguous fp32 -> bf16x8 fragment
__device__ __forceinline__ bf8 cvt8(const float* __restrict__ p){
  f4 u = *(const f4*)p;
  f4 v = *(const f4*)(p + 4);
  bf8 r;
  r[0]=(__bf16)u[0]; r[1]=(__bf16)u[1]; r[2]=(__bf16)u[2]; r[3]=(__bf16)u[3];
  r[4]=(__bf16)v[0]; r[5]=(__bf16)v[1]; r[6]=(__bf16)v[2]; r[7]=(__bf16)v[3];
  return r;
}

// B fragment from pre-transposed bf16 weight WT[out][k]; ptr must be at (col0,k0)
__device__ __forceinline__ bf8 bfragT(const __bf16* __restrict__ WT, int ldk, int lane){
  const __bf16* p = WT + (size_t)(lane & 15) * ldk + ((lane >> 4) << 3);
  return *(const bf8*)p;
}

// ---------------- weight prep: W[K][M] (fp32) -> WT[M][K] (bf16) ----------------
__global__ void k_transpose(const float* __restrict__ W, __bf16* __restrict__ WT, int K, int M){
  int idx = blockIdx.x * 256 + threadIdx.x;
  if (idx >= K * M) return;
  int m = idx / K, k = idx - m * K;
  WT[idx] = (__bf16)W[(size_t)k * M + m];
}

// ---------------- CSR build ----------------
__global__ void k_hist(const int* __restrict__ dst, int* __restrict__ deg, int E){
  int i = blockIdx.x * 256 + threadIdx.x;
  if (i < E) atomicAdd(&deg[dst[i]], 1);
}

__global__ __launch_bounds__(1024) void k_scan(const int* __restrict__ deg,
    int* __restrict__ off, int* __restrict__ cursor, int N)
{
  __shared__ int part[1024];
  int t = threadIdx.x;
  int C = (N + 1023) >> 10;
  int base = t * C;
  int sum = 0;
  for (int i = 0; i < C; ++i){ int idx = base + i; if (idx < N) sum += deg[idx]; }
  part[t] = sum;
  __syncthreads();
  for (int d = 1; d < 1024; d <<= 1){
    int add = (t >= d) ? part[t - d] : 0;
    __syncthreads();
    part[t] += add;
    __syncthreads();
  }
  int run = (t == 0) ? 0 : part[t - 1];
  for (int i = 0; i < C; ++i){
    int idx = base + i;
    if (idx < N){ off[idx] = run; cursor[idx] = run; run += deg[idx]; }
  }
}

// ---------------- K1: Q,K,V = h @ Wq/Wk/Wv ----------------
__global__ __launch_bounds__(256) void k_qkv(const float* __restrict__ h,
    const __bf16* __restrict__ WqT, const __bf16* __restrict__ WkT, const __bf16* __restrict__ WvT,
    float* __restrict__ Q, float* __restrict__ K, float* __restrict__ V, int N)
{
  int lane = threadIdx.x & 63;
  int r0 = (blockIdx.x * 4 + (threadIdx.x >> 6)) * 16;
  if (r0 + 16 > N) return;
  bf8 a[4];
  int arow = r0 + (lane & 15);
  int koff = (lane >> 4) << 3;
#pragma unroll
  for (int kt = 0; kt < 4; ++kt)
    a[kt] = cvt8(h + (size_t)arow * DM + kt * 32 + koff);

  const __bf16* Ws[3] = {WqT, WkT, WvT};
  float* Os[3] = {Q, K, V};
  int crow = r0 + ((lane >> 4) << 2);
  int ccol = lane & 15;
#pragma unroll
  for (int o = 0; o < 3; ++o){
#pragma unroll
    for (int nt = 0; nt < 8; ++nt){
      f4 acc = {0.f, 0.f, 0.f, 0.f};
#pragma unroll
      for (int kt = 0; kt < 4; ++kt)
        acc = mfma16(a[kt], bfragT(Ws[o] + (size_t)(nt * 16) * DM + kt * 32, DM, lane), acc);
      float* outp = Os[o] + (size_t)crow * DM + nt * 16 + ccol;
      outp[0] = acc[0]; outp[DM] = acc[1]; outp[2 * DM] = acc[2]; outp[3 * DM] = acc[3];
    }
  }
}

// ---------------- K2: fused Eh GEMM + edge scoring (coalesced row gathers) ----------------
__global__ __launch_bounds__(256) void k_edge(const float* __restrict__ e,
    const __bf16* __restrict__ WeT,
    const float* __restrict__ Qf, const float* __restrict__ Kf,
    const int* __restrict__ src, const int* __restrict__ dst,
    int* __restrict__ cursor, int* __restrict__ sSrc, float* __restrict__ sS, int E)
{
  __shared__ float Eh[64][132];     // +4 pad: breaks bank conflicts on f4 row reads
  __shared__ int s_src[64], s_dst[64], s_slot[64];
  int tid = threadIdx.x, lane = tid & 63, wave = tid >> 6;
  int e0 = blockIdx.x * 64;
  // edge meta + CSR slot allocation (overlaps with GEMM below; no extra barrier)
  if (tid < 64){
    int ei = e0 + tid;
    bool v = ei < E;
    int sj = v ? src[ei] : 0;
    int dj = v ? dst[ei] : 0;
    s_src[tid] = sj;
    s_dst[tid] = dj;
    int slot = v ? atomicAdd(&cursor[dj], 1) : 0;
    s_slot[tid] = slot;
    if (v) sSrc[slot] = sj;
  }
  // phase 1: Eh tile = e[e0:e0+64] @ We  (each wave does 16 rows)
  int er = e0 + wave * 16 + (lane & 15);
  if (er >= E) er = E - 1;
  int koff = (lane >> 4) << 3;
  bf8 a[4];
#pragma unroll
  for (int kt = 0; kt < 4; ++kt)
    a[kt] = cvt8(e + (size_t)er * DM + kt * 32 + koff);
  int lrow = wave * 16 + ((lane >> 4) << 2);
  int ccol = lane & 15;
#pragma unroll
  for (int nt = 0; nt < 8; ++nt){
    f4 acc = {0.f, 0.f, 0.f, 0.f};
#pragma unroll
    for (int kt = 0; kt < 4; ++kt)
      acc = mfma16(a[kt], bfragT(WeT + (size_t)(nt * 16) * DM + kt * 32, DM, lane), acc);
    int col = nt * 16 + ccol;
#pragma unroll
    for (int r = 0; r < 4; ++r) Eh[lrow + r][col] = acc[r];
  }
  __syncthreads();

  // phase 2: one edge per 32 lanes; coalesced 512B row reads of K[src], Q[dst]
  int half = lane >> 5;        // which edge of the pair
  int l32 = lane & 31;
  int hh = l32 >> 2;           // head owned by this 4-lane group
#pragma unroll 2
  for (int i = 0; i < 8; ++i){
    int j = wave * 16 + i * 2 + half;
    if (e0 + j >= E) continue;
    int sj = s_src[j], dj = s_dst[j];
    f4 kv = *(const f4*)(Kf + (size_t)sj * DM + l32 * 4);
    f4 qv = *(const f4*)(Qf + (size_t)dj * DM + l32 * 4);
    f4 ev = *(const f4*)&Eh[j][l32 * 4];
    float dsum = kv[0]*qv[0]*ev[0] + kv[1]*qv[1]*ev[1] + kv[2]*qv[2]*ev[2] + kv[3]*qv[3]*ev[3];
    dsum += __shfl_xor(dsum, 1);
    dsum += __shfl_xor(dsum, 2);
    if ((l32 & 3) == 0){
      float dd = fminf(5.f, fmaxf(-5.f, dsum * 0.25f));
      sS[(size_t)s_slot[j] * NH + hh] = __expf(dd);
    }
  }
}

// ---------------- K2c: per-node gather reduction (32 lanes per node) ----------------
__global__ __launch_bounds__(256) void k_gather(const int* __restrict__ off,
    const int* __restrict__ cend, const int* __restrict__ sSrc, const float* __restrict__ sS,
    const float* __restrict__ Vf, float* __restrict__ hattn, int N)
{
  int lane = threadIdx.x & 63;
  int half = lane >> 5, l32 = lane & 31;
  int node = blockIdx.x * 8 + (threadIdx.x >> 6) * 2 + half;
  if (node >= N) return;
  int start = off[node], end = cend[node];   // cursor after k_edge == end of range
  int hh = l32 >> 2;
  f4 acc = {0.f, 0.f, 0.f, 0.f};
  float z = 0.f;
  int sj_next = (start < end) ? sSrc[start] : 0;
  for (int eid = start; eid < end; ++eid){
    int sj = sj_next;
    if (eid + 1 < end) sj_next = sSrc[eid + 1];
    float s = sS[(size_t)eid * NH + hh];
    f4 v = *(const f4*)(Vf + (size_t)sj * DM + l32 * 4);
    acc[0] += s * v[0]; acc[1] += s * v[1]; acc[2] += s * v[2]; acc[3] += s * v[3];
    z += s;
  }
  float invz = 1.f / (z + 1e-6f);
  f4 o;
  o[0] = acc[0] * invz; o[1] = acc[1] * invz; o[2] = acc[2] * invz; o[3] = acc[3] * invz;
  *(f4*)(hattn + (size_t)node * DM + l32 * 4) = o;
}

// ---------------- K3: h2 = h + h_attn @ Wo + bo ----------------
__global__ __launch_bounds__(256) void k_attnout(const float* __restrict__ hattn,
    const float* __restrict__ h,
    const __bf16* __restrict__ WoT, const float* __restrict__ bo,
    float* __restrict__ h2, int N)
{
  int lane = threadIdx.x & 63;
  int r0 = (blockIdx.x * 4 + (threadIdx.x >> 6)) * 16;
  if (r0 + 16 > N) return;
  int arow = r0 + (lane & 15);
  int kof = (lane >> 4) << 3;
  bf8 a[4];
#pragma unroll
  for (int kt = 0; kt < 4; ++kt)
    a[kt] = cvt8(hattn + (size_t)arow * DM + kt * 32 + kof);
  int crow = r0 + ((lane >> 4) << 2);
  int ccol = lane & 15;
#pragma unroll
  for (int nt = 0; nt < 8; ++nt){
    f4 acc = {0.f, 0.f, 0.f, 0.f};
#pragma unroll
    for (int kt = 0; kt < 4; ++kt)
      acc = mfma16(a[kt], bfragT(WoT + (size_t)(nt * 16) * DM + kt * 32, DM, lane), acc);
    int col = nt * 16 + ccol;
    float bb = bo[col];
#pragma unroll
    for (int r = 0; r < 4; ++r){
      size_t idx = (size_t)(crow + r) * DM + col;
      h2[idx] = h[idx] + acc[r] + bb;
    }
  }
}

// ---------------- BN stats / coef / apply ----------------
__global__ __launch_bounds__(256) void k_bnstats(const float* __restrict__ x,
    float* __restrict__ s1, float* __restrict__ s2, int N)
{
  __shared__ float p1[256], p2[256];
  int c = threadIdx.x & 127, g = threadIdx.x >> 7;
  float a1 = 0.f, a2 = 0.f;
  for (int r = blockIdx.x * 2 + g; r < N; r += gridDim.x * 2){
    float v = x[(size_t)r * DM + c];
    a1 += v; a2 += v * v;
  }
  p1[threadIdx.x] = a1; p2[threadIdx.x] = a2;
  __syncthreads();
  if (g == 0){
    atomicAdd(&s1[c], p1[threadIdx.x] + p1[threadIdx.x + 128]);
    atomicAdd(&s2[c], p2[threadIdx.x] + p2[threadIdx.x + 128]);
  }
}

__global__ void k_bncoef(const float* __restrict__ s1, const float* __restrict__ s2,
    const float* __restrict__ gam, const float* __restrict__ bet,
    float* __restrict__ cs, float* __restrict__ cb, int N)
{
  int c = threadIdx.x;
  if (c >= DM) return;
  float mean = s1[c] / (float)N;
  float var  = s2[c] / (float)N - mean * mean;
  float rs   = rsqrtf(var + 1e-5f);
  float sc   = gam[c] * rs;
  cs[c] = sc;
  cb[c] = bet[c] - mean * sc;
}

__global__ void k_bnapply(float* __restrict__ t, const float* __restrict__ cs,
    const float* __restrict__ cb, long long total4)
{
  long long i = (long long)blockIdx.x * blockDim.x + threadIdx.x;
  if (i >= total4) return;
  f4* p = (f4*)t + i;
  f4 v = *p;
  int c = (int)((i * 4) & (DM - 1));
  v[0] = v[0] * cs[c]     + cb[c];
  v[1] = v[1] * cs[c + 1] + cb[c + 1];
  v[2] = v[2] * cs[c + 2] + cb[c + 2];
  v[3] = v[3] * cs[c + 3] + cb[c + 3];
  *p = v;
}

// ---------------- K6: FFN fused (x=BN1(h2); t = x + relu(x@W1+b1)@W2 + b2) ----------------
__global__ __launch_bounds__(256) void k_ffn(const float* __restrict__ h2,
    const float* __restrict__ c1s, const float* __restrict__ c1b,
    const __bf16* __restrict__ W1T, const float* __restrict__ b1,
    const __bf16* __restrict__ W2T, const float* __restrict__ b2,
    float* __restrict__ t, int N)
{
  __shared__ __bf16 hid[4][16][256];   // 32 KiB
  int lane = threadIdx.x & 63, wave = threadIdx.x >> 6;
  int r0 = (blockIdx.x * 4 + wave) * 16;
  bool active = (r0 + 16 <= N);
  int r0c = active ? r0 : 0;

  int arow = r0c + (lane & 15);
  int kof = (lane >> 4) << 3;
  bf8 a[4];
#pragma unroll
  for (int kt = 0; kt < 4; ++kt){
    int kb = kt * 32 + kof;
    const f4* p  = (const f4*)(h2 + (size_t)arow * DM + kb);
    const f4* ps = (const f4*)(c1s + kb);
    const f4* pb = (const f4*)(c1b + kb);
    f4 u = p[0], v = p[1], s0 = ps[0], s1v = ps[1], b0 = pb[0], b1v = pb[1];
    bf8 r;
    r[0]=(__bf16)(u[0]*s0[0]+b0[0]); r[1]=(__bf16)(u[1]*s0[1]+b0[1]);
    r[2]=(__bf16)(u[2]*s0[2]+b0[2]); r[3]=(__bf16)(u[3]*s0[3]+b0[3]);
    r[4]=(__bf16)(v[0]*s1v[0]+b1v[0]); r[5]=(__bf16)(v[1]*s1v[1]+b1v[1]);
    r[6]=(__bf16)(v[2]*s1v[2]+b1v[2]); r[7]=(__bf16)(v[3]*s1v[3]+b1v[3]);
    a[kt] = r;
  }
  int lr = (lane >> 4) << 2;
  int ccol = lane & 15;
  // GEMM1: 16x256, relu -> LDS (bf16)
#pragma unroll
  for (int nt = 0; nt < 16; ++nt){
    f4 acc = {0.f, 0.f, 0.f, 0.f};
#pragma unroll
    for (int kt = 0; kt < 4; ++kt)
      acc = mfma16(a[kt], bfragT(W1T + (size_t)(nt * 16) * DM + kt * 32, DM, lane), acc);
    int col = nt * 16 + ccol;
    float bb = b1[col];
#pragma unroll
    for (int r = 0; r < 4; ++r)
      hid[wave][lr + r][col] = (__bf16)fmaxf(acc[r] + bb, 0.f);
  }
  __syncthreads();
  // GEMM2: 16x128, K=256
  f4 acc2[8];
#pragma unroll
  for (int nt = 0; nt < 8; ++nt){ acc2[nt][0]=0.f; acc2[nt][1]=0.f; acc2[nt][2]=0.f; acc2[nt][3]=0.f; }
#pragma unroll
  for (int kt = 0; kt < 8; ++kt){
    bf8 a2 = *(const bf8*)&hid[wave][lane & 15][kt * 32 + kof];
#pragma unroll
    for (int nt = 0; nt < 8; ++nt)
      acc2[nt] = mfma16(a2, bfragT(W2T + (size_t)(nt * 16) * 256 + kt * 32, 256, lane), acc2[nt]);
  }
  if (!active) return;
  int crow = r0 + lr;
#pragma unroll
  for (int nt = 0; nt < 8; ++nt){
    int col = nt * 16 + ccol;
    float bb = b2[col], sc = c1s[col], sb = c1b[col];
#pragma unroll
    for (int r = 0; r < 4; ++r){
      size_t idx = (size_t)(crow + r) * DM + col;
      float xres = h2[idx] * sc + sb;
      t[idx] = acc2[nt][r] + bb + xres;
    }
  }
}

// ---------------- host ----------------
extern "C" void kernel_launch(void* const* d_in, const int* in_sizes, int n_in,
                              void* d_out, int out_size, void* d_ws, size_t ws_size,
                              hipStream_t stream)
{
  const float* h    = (const float*)d_in[0];
  const float* e    = (const float*)d_in[2];
  const float* Wq   = (const float*)d_in[3];
  const float* Wk   = (const float*)d_in[4];
  const float* We   = (const float*)d_in[5];
  const float* Wv   = (const float*)d_in[6];
  const float* Wo   = (const float*)d_in[7];
  const float* bo   = (const float*)d_in[8];
  const float* bn1g = (const float*)d_in[9];
  const float* bn1b = (const float*)d_in[10];
  const float* bn2g = (const float*)d_in[11];
  const float* bn2b = (const float*)d_in[12];
  const float* W1   = (const float*)d_in[13];
  const float* b1   = (const float*)d_in[14];
  const float* W2   = (const float*)d_in[15];
  const float* b2   = (const float*)d_in[16];
  const int*   src  = (const int*)d_in[17];
  const int*   dst  = (const int*)d_in[18];

  int N = in_sizes[0] / DM;
  int E = in_sizes[2] / DM;
  float* out = (float*)d_out;

  char* ws = (char*)d_ws;
  size_t off_b = 0;
  auto alloc = [&](size_t bytes) -> char* {
    char* r = ws + off_b;
    off_b += (bytes + 255) & ~(size_t)255;
    return r;
  };
  float* Qf    = (float*)alloc((size_t)N * DM * 4);
  float* Kf    = (float*)alloc((size_t)N * DM * 4);
  float* Vf    = (float*)alloc((size_t)N * DM * 4);
  float* hattn = (float*)alloc((size_t)N * DM * 4);
  float* h2    = (float*)alloc((size_t)N * DM * 4);
  int*   deg    = (int*)alloc((size_t)N * 4);
  int*   offs   = (int*)alloc((size_t)N * 4);
  int*   cursor = (int*)alloc((size_t)N * 4);
  int*   sSrc   = (int*)alloc((size_t)E * 4);
  float* sS     = (float*)alloc((size_t)E * NH * 4);
  float* stats = (float*)alloc(1024 * 4);   // s1a s2a s1b s2b c1s c1b c2s c2b
  float* s1a = stats, *s2a = stats + 128, *s1b = stats + 256, *s2b = stats + 384;
  float* c1s = stats + 512, *c1b = stats + 640, *c2s = stats + 768, *c2b = stats + 896;
  __bf16* WqT = (__bf16*)alloc(16384 * 2);
  __bf16* WkT = (__bf16*)alloc(16384 * 2);
  __bf16* WvT = (__bf16*)alloc(16384 * 2);
  __bf16* WeT = (__bf16*)alloc(16384 * 2);
  __bf16* WoT = (__bf16*)alloc(16384 * 2);
  __bf16* W1T = (__bf16*)alloc(32768 * 2);
  __bf16* W2T = (__bf16*)alloc(32768 * 2);

  hipMemsetAsync(deg, 0, (size_t)N * 4, stream);
  hipMemsetAsync(stats, 0, 512 * 4, stream);

  k_transpose<<<64, 256, 0, stream>>>(Wq, WqT, DM, DM);
  k_transpose<<<64, 256, 0, stream>>>(Wk, WkT, DM, DM);
  k_transpose<<<64, 256, 0, stream>>>(Wv, WvT, DM, DM);
  k_transpose<<<64, 256, 0, stream>>>(We, WeT, DM, DM);
  k_transpose<<<64, 256, 0, stream>>>(Wo, WoT, DM, DM);
  k_transpose<<<128, 256, 0, stream>>>(W1, W1T, DM, 256);
  k_transpose<<<128, 256, 0, stream>>>(W2, W2T, 256, DM);

  k_hist<<<(E + 255) / 256, 256, 0, stream>>>(dst, deg, E);
  k_scan<<<1, 1024, 0, stream>>>(deg, offs, cursor, N);

  int rowblocks = (N / 16 + 3) / 4;
  k_qkv<<<rowblocks, 256, 0, stream>>>(h, WqT, WkT, WvT, Qf, Kf, Vf, N);
  k_edge<<<(E + 63) / 64, 256, 0, stream>>>(e, WeT, Qf, Kf, src, dst, cursor, sSrc, sS, E);
  k_gather<<<(N + 7) / 8, 256, 0, stream>>>(offs, cursor, sSrc, sS, Vf, hattn, N);
  k_attnout<<<rowblocks, 256, 0, stream>>>(hattn, h, WoT, bo, h2, N);
  k_bnstats<<<256, 256, 0, stream>>>(h2, s1a, s2a, N);
  k_bncoef<<<1, 128, 0, stream>>>(s1a, s2a, bn1g, bn1b, c1s, c1b, N);
  k_ffn<<<rowblocks, 256, 0, stream>>>(h2, c1s, c1b, W1T, b1, W2T, b2, out, N);
  k_bnstats<<<256, 256, 0, stream>>>(out, s1b, s2b, N);
  k_bncoef<<<1, 128, 0, stream>>>(s1b, s2b, bn2g, bn2b, c2s, c2b, N);
  long long total4 = (long long)N * DM / 4;
  k_bnapply<<<(int)((total4 + 255) / 256), 256, 0, stream>>>(out, c2s, c2b, total4);
}

// Round 4
// 760.302 us; speedup vs baseline: 1.1112x; 1.1112x over previous
//
#include <hip/hip_runtime.h>

#define DM 128
#define NH 8
#define DH 16

typedef __bf16 bf8 __attribute__((ext_vector_type(8)));
typedef __bf16 bf4 __attribute__((ext_vector_type(4)));
typedef float  f4  __attribute__((ext_vector_type(4)));

__device__ __forceinline__ f4 mfma16(bf8 a, bf8 b, f4 c){
  return __builtin_amdgcn_mfma_f32_16x16x32_bf16(a, b, c, 0, 0, 0);
}

// convert 8 contiguous fp32 -> bf16x8 fragment
__device__ __forceinline__ bf8 cvt8(const float* __restrict__ p){
  f4 u = *(const f4*)p;
  f4 v = *(const f4*)(p + 4);
  bf8 r;
  r[0]=(__bf16)u[0]; r[1]=(__bf16)u[1]; r[2]=(__bf16)u[2]; r[3]=(__bf16)u[3];
  r[4]=(__bf16)v[0]; r[5]=(__bf16)v[1]; r[6]=(__bf16)v[2]; r[7]=(__bf16)v[3];
  return r;
}

// B fragment from pre-transposed bf16 weight WT[out][k]; ptr must be at (col0,k0)
__device__ __forceinline__ bf8 bfragT(const __bf16* __restrict__ WT, int ldk, int lane){
  const __bf16* p = WT + (size_t)(lane & 15) * ldk + ((lane >> 4) << 3);
  return *(const bf8*)p;
}

// ---------------- weight prep: W[K][M] (fp32) -> WT[M][K] (bf16) ----------------
__global__ void k_transpose(const float* __restrict__ W, __bf16* __restrict__ WT, int K, int M){
  int idx = blockIdx.x * 256 + threadIdx.x;
  if (idx >= K * M) return;
  int m = idx / K, k = idx - m * K;
  WT[idx] = (__bf16)W[(size_t)k * M + m];
}

// ---------------- CSR build ----------------
__global__ void k_hist(const int* __restrict__ dst, int* __restrict__ deg, int E){
  int i = blockIdx.x * 256 + threadIdx.x;
  if (i < E) atomicAdd(&deg[dst[i]], 1);
}

__global__ __launch_bounds__(1024) void k_scan(const int* __restrict__ deg,
    int* __restrict__ off, int* __restrict__ cursor, int N)
{
  __shared__ int part[1024];
  int t = threadIdx.x;
  int C = (N + 1023) >> 10;
  int base = t * C;
  int sum = 0;
  for (int i = 0; i < C; ++i){ int idx = base + i; if (idx < N) sum += deg[idx]; }
  part[t] = sum;
  __syncthreads();
  for (int d = 1; d < 1024; d <<= 1){
    int add = (t >= d) ? part[t - d] : 0;
    __syncthreads();
    part[t] += add;
    __syncthreads();
  }
  int run = (t == 0) ? 0 : part[t - 1];
  for (int i = 0; i < C; ++i){
    int idx = base + i;
    if (idx < N){ off[idx] = run; cursor[idx] = run; run += deg[idx]; }
  }
}

// ---------------- K1: Q,K,V = h @ Wq/Wk/Wv  (bf16 outputs) ----------------
__global__ __launch_bounds__(256) void k_qkv(const float* __restrict__ h,
    const __bf16* __restrict__ WqT, const __bf16* __restrict__ WkT, const __bf16* __restrict__ WvT,
    __bf16* __restrict__ Q, __bf16* __restrict__ K, __bf16* __restrict__ V, int N)
{
  int lane = threadIdx.x & 63;
  int r0 = (blockIdx.x * 4 + (threadIdx.x >> 6)) * 16;
  if (r0 + 16 > N) return;
  bf8 a[4];
  int arow = r0 + (lane & 15);
  int koff = (lane >> 4) << 3;
#pragma unroll
  for (int kt = 0; kt < 4; ++kt)
    a[kt] = cvt8(h + (size_t)arow * DM + kt * 32 + koff);

  const __bf16* Ws[3] = {WqT, WkT, WvT};
  __bf16* Os[3] = {Q, K, V};
  int crow = r0 + ((lane >> 4) << 2);
  int ccol = lane & 15;
#pragma unroll
  for (int o = 0; o < 3; ++o){
#pragma unroll
    for (int nt = 0; nt < 8; ++nt){
      f4 acc = {0.f, 0.f, 0.f, 0.f};
#pragma unroll
      for (int kt = 0; kt < 4; ++kt)
        acc = mfma16(a[kt], bfragT(Ws[o] + (size_t)(nt * 16) * DM + kt * 32, DM, lane), acc);
      __bf16* outp = Os[o] + (size_t)crow * DM + nt * 16 + ccol;
      outp[0] = (__bf16)acc[0]; outp[DM] = (__bf16)acc[1];
      outp[2 * DM] = (__bf16)acc[2]; outp[3 * DM] = (__bf16)acc[3];
    }
  }
}

// ---------------- K2: fused Eh GEMM + edge scoring ----------------
__global__ __launch_bounds__(256) void k_edge(const float* __restrict__ e,
    const __bf16* __restrict__ WeT,
    const __bf16* __restrict__ Qb, const __bf16* __restrict__ Kb,
    const int* __restrict__ src, const int* __restrict__ dst,
    int* __restrict__ cursor, int* __restrict__ sSrc, float* __restrict__ sS, int E)
{
  __shared__ __bf16 Eh[64][132];    // bf16: 17 KB -> 8 blocks/CU (occupancy ~100%)
  __shared__ int s_src[64], s_dst[64], s_slot[64];
  int tid = threadIdx.x, lane = tid & 63, wave = tid >> 6;
  int e0 = blockIdx.x * 64;
  // edge meta + CSR slot allocation (overlaps with GEMM below)
  if (tid < 64){
    int ei = e0 + tid;
    bool v = ei < E;
    int sj = v ? src[ei] : 0;
    int dj = v ? dst[ei] : 0;
    s_src[tid] = sj;
    s_dst[tid] = dj;
    int slot = v ? atomicAdd(&cursor[dj], 1) : 0;
    s_slot[tid] = slot;
    if (v) sSrc[slot] = sj;
  }
  // phase 1: Eh tile = e[e0:e0+64] @ We  (each wave does 16 rows)
  int er = e0 + wave * 16 + (lane & 15);
  if (er >= E) er = E - 1;
  int koff = (lane >> 4) << 3;
  bf8 a[4];
#pragma unroll
  for (int kt = 0; kt < 4; ++kt)
    a[kt] = cvt8(e + (size_t)er * DM + kt * 32 + koff);
  int lrow = wave * 16 + ((lane >> 4) << 2);
  int ccol = lane & 15;
#pragma unroll
  for (int nt = 0; nt < 8; ++nt){
    f4 acc = {0.f, 0.f, 0.f, 0.f};
#pragma unroll
    for (int kt = 0; kt < 4; ++kt)
      acc = mfma16(a[kt], bfragT(WeT + (size_t)(nt * 16) * DM + kt * 32, DM, lane), acc);
    int col = nt * 16 + ccol;
#pragma unroll
    for (int r = 0; r < 4; ++r) Eh[lrow + r][col] = (__bf16)acc[r];
  }
  __syncthreads();

  // phase 2: one edge per 32 lanes; coalesced 256B bf16 row reads of K[src], Q[dst]
  int half = lane >> 5;
  int l32 = lane & 31;
  int hh = l32 >> 2;            // head owned by this 4-lane group
#pragma unroll 4
  for (int i = 0; i < 8; ++i){
    int j = wave * 16 + i * 2 + half;
    if (e0 + j >= E) continue;
    int sj = s_src[j], dj = s_dst[j];
    bf4 kv = *(const bf4*)(Kb + (size_t)sj * DM + l32 * 4);
    bf4 qv = *(const bf4*)(Qb + (size_t)dj * DM + l32 * 4);
    bf4 ev = *(const bf4*)&Eh[j][l32 * 4];
    float dsum = (float)kv[0]*(float)qv[0]*(float)ev[0]
               + (float)kv[1]*(float)qv[1]*(float)ev[1]
               + (float)kv[2]*(float)qv[2]*(float)ev[2]
               + (float)kv[3]*(float)qv[3]*(float)ev[3];
    dsum += __shfl_xor(dsum, 1);
    dsum += __shfl_xor(dsum, 2);
    if ((l32 & 3) == 0){
      float dd = fminf(5.f, fmaxf(-5.f, dsum * 0.25f));
      sS[(size_t)s_slot[j] * NH + hh] = __expf(dd);
    }
  }
}

// ---------------- K2c: per-node gather reduction (32 lanes/node, 2-edge unroll) ----------------
__global__ __launch_bounds__(256) void k_gather(const int* __restrict__ off,
    const int* __restrict__ cend, const int* __restrict__ sSrc, const float* __restrict__ sS,
    const __bf16* __restrict__ Vb, __bf16* __restrict__ hattn, int N)
{
  int lane = threadIdx.x & 63;
  int half = lane >> 5, l32 = lane & 31;
  int node = blockIdx.x * 8 + (threadIdx.x >> 6) * 2 + half;
  if (node >= N) return;
  int start = off[node], end = cend[node];
  int hh = l32 >> 2;
  float a0 = 0.f, a1 = 0.f, a2 = 0.f, a3 = 0.f, z = 0.f;
  int i = start;
  int sj0 = (i < end) ? sSrc[i] : 0;
  int sj1 = (i + 1 < end) ? sSrc[i + 1] : 0;
  for (; i + 1 < end; i += 2){
    int sj2 = (i + 2 < end) ? sSrc[i + 2] : 0;
    int sj3 = (i + 3 < end) ? sSrc[i + 3] : 0;
    float s0 = sS[(size_t)i * NH + hh];
    float s1 = sS[(size_t)(i + 1) * NH + hh];
    bf4 v0 = *(const bf4*)(Vb + (size_t)sj0 * DM + l32 * 4);
    bf4 v1 = *(const bf4*)(Vb + (size_t)sj1 * DM + l32 * 4);
    a0 += s0 * (float)v0[0] + s1 * (float)v1[0];
    a1 += s0 * (float)v0[1] + s1 * (float)v1[1];
    a2 += s0 * (float)v0[2] + s1 * (float)v1[2];
    a3 += s0 * (float)v0[3] + s1 * (float)v1[3];
    z += s0 + s1;
    sj0 = sj2; sj1 = sj3;
  }
  if (i < end){
    float s0 = sS[(size_t)i * NH + hh];
    bf4 v0 = *(const bf4*)(Vb + (size_t)sj0 * DM + l32 * 4);
    a0 += s0 * (float)v0[0]; a1 += s0 * (float)v0[1];
    a2 += s0 * (float)v0[2]; a3 += s0 * (float)v0[3];
    z += s0;
  }
  float invz = 1.f / (z + 1e-6f);
  bf4 o;
  o[0] = (__bf16)(a0 * invz); o[1] = (__bf16)(a1 * invz);
  o[2] = (__bf16)(a2 * invz); o[3] = (__bf16)(a3 * invz);
  *(bf4*)(hattn + (size_t)node * DM + l32 * 4) = o;
}

// ---------------- K3: h2 = h + h_attn @ Wo + bo ----------------
__global__ __launch_bounds__(256) void k_attnout(const __bf16* __restrict__ hattn,
    const float* __restrict__ h,
    const __bf16* __restrict__ WoT, const float* __restrict__ bo,
    float* __restrict__ h2, int N)
{
  int lane = threadIdx.x & 63;
  int r0 = (blockIdx.x * 4 + (threadIdx.x >> 6)) * 16;
  if (r0 + 16 > N) return;
  int arow = r0 + (lane & 15);
  int kof = (lane >> 4) << 3;
  bf8 a[4];
#pragma unroll
  for (int kt = 0; kt < 4; ++kt)
    a[kt] = *(const bf8*)(hattn + (size_t)arow * DM + kt * 32 + kof);
  int crow = r0 + ((lane >> 4) << 2);
  int ccol = lane & 15;
#pragma unroll
  for (int nt = 0; nt < 8; ++nt){
    f4 acc = {0.f, 0.f, 0.f, 0.f};
#pragma unroll
    for (int kt = 0; kt < 4; ++kt)
      acc = mfma16(a[kt], bfragT(WoT + (size_t)(nt * 16) * DM + kt * 32, DM, lane), acc);
    int col = nt * 16 + ccol;
    float bb = bo[col];
#pragma unroll
    for (int r = 0; r < 4; ++r){
      size_t idx = (size_t)(crow + r) * DM + col;
      h2[idx] = h[idx] + acc[r] + bb;
    }
  }
}

// ---------------- BN stats / coef / apply ----------------
__global__ __launch_bounds__(256) void k_bnstats(const float* __restrict__ x,
    float* __restrict__ s1, float* __restrict__ s2, int N)
{
  __shared__ float p1[256], p2[256];
  int c = threadIdx.x & 127, g = threadIdx.x >> 7;
  float a1 = 0.f, a2 = 0.f;
  for (int r = blockIdx.x * 2 + g; r < N; r += gridDim.x * 2){
    float v = x[(size_t)r * DM + c];
    a1 += v; a2 += v * v;
  }
  p1[threadIdx.x] = a1; p2[threadIdx.x] = a2;
  __syncthreads();
  if (g == 0){
    atomicAdd(&s1[c], p1[threadIdx.x] + p1[threadIdx.x + 128]);
    atomicAdd(&s2[c], p2[threadIdx.x] + p2[threadIdx.x + 128]);
  }
}

__global__ void k_bncoef(const float* __restrict__ s1, const float* __restrict__ s2,
    const float* __restrict__ gam, const float* __restrict__ bet,
    float* __restrict__ cs, float* __restrict__ cb, int N)
{
  int c = threadIdx.x;
  if (c >= DM) return;
  float mean = s1[c] / (float)N;
  float var  = s2[c] / (float)N - mean * mean;
  float rs   = rsqrtf(var + 1e-5f);
  float sc   = gam[c] * rs;
  cs[c] = sc;
  cb[c] = bet[c] - mean * sc;
}

__global__ void k_bnapply(float* __restrict__ t, const float* __restrict__ cs,
    const float* __restrict__ cb, long long total4)
{
  long long i = (long long)blockIdx.x * blockDim.x + threadIdx.x;
  if (i >= total4) return;
  f4* p = (f4*)t + i;
  f4 v = *p;
  int c = (int)((i * 4) & (DM - 1));
  v[0] = v[0] * cs[c]     + cb[c];
  v[1] = v[1] * cs[c + 1] + cb[c + 1];
  v[2] = v[2] * cs[c + 2] + cb[c + 2];
  v[3] = v[3] * cs[c + 3] + cb[c + 3];
  *p = v;
}

// ---------------- K6: FFN fused (x=BN1(h2); t = x + relu(x@W1+b1)@W2 + b2) ----------------
__global__ __launch_bounds__(256) void k_ffn(const float* __restrict__ h2,
    const float* __restrict__ c1s, const float* __restrict__ c1b,
    const __bf16* __restrict__ W1T, const float* __restrict__ b1,
    const __bf16* __restrict__ W2T, const float* __restrict__ b2,
    float* __restrict__ t, int N)
{
  __shared__ __bf16 hid[4][16][256];   // 32 KiB
  int lane = threadIdx.x & 63, wave = threadIdx.x >> 6;
  int r0 = (blockIdx.x * 4 + wave) * 16;
  bool active = (r0 + 16 <= N);
  int r0c = active ? r0 : 0;

  int arow = r0c + (lane & 15);
  int kof = (lane >> 4) << 3;
  bf8 a[4];
#pragma unroll
  for (int kt = 0; kt < 4; ++kt){
    int kb = kt * 32 + kof;
    const f4* p  = (const f4*)(h2 + (size_t)arow * DM + kb);
    const f4* ps = (const f4*)(c1s + kb);
    const f4* pb = (const f4*)(c1b + kb);
    f4 u = p[0], v = p[1], s0 = ps[0], s1v = ps[1], b0 = pb[0], b1v = pb[1];
    bf8 r;
    r[0]=(__bf16)(u[0]*s0[0]+b0[0]); r[1]=(__bf16)(u[1]*s0[1]+b0[1]);
    r[2]=(__bf16)(u[2]*s0[2]+b0[2]); r[3]=(__bf16)(u[3]*s0[3]+b0[3]);
    r[4]=(__bf16)(v[0]*s1v[0]+b1v[0]); r[5]=(__bf16)(v[1]*s1v[1]+b1v[1]);
    r[6]=(__bf16)(v[2]*s1v[2]+b1v[2]); r[7]=(__bf16)(v[3]*s1v[3]+b1v[3]);
    a[kt] = r;
  }
  int lr = (lane >> 4) << 2;
  int ccol = lane & 15;
  // GEMM1: 16x256, relu -> LDS (bf16)
#pragma unroll
  for (int nt = 0; nt < 16; ++nt){
    f4 acc = {0.f, 0.f, 0.f, 0.f};
#pragma unroll
    for (int kt = 0; kt < 4; ++kt)
      acc = mfma16(a[kt], bfragT(W1T + (size_t)(nt * 16) * DM + kt * 32, DM, lane), acc);
    int col = nt * 16 + ccol;
    float bb = b1[col];
#pragma unroll
    for (int r = 0; r < 4; ++r)
      hid[wave][lr + r][col] = (__bf16)fmaxf(acc[r] + bb, 0.f);
  }
  __syncthreads();
  // GEMM2: 16x128, K=256
  f4 acc2[8];
#pragma unroll
  for (int nt = 0; nt < 8; ++nt){ acc2[nt][0]=0.f; acc2[nt][1]=0.f; acc2[nt][2]=0.f; acc2[nt][3]=0.f; }
#pragma unroll
  for (int kt = 0; kt < 8; ++kt){
    bf8 a2 = *(const bf8*)&hid[wave][lane & 15][kt * 32 + kof];
#pragma unroll
    for (int nt = 0; nt < 8; ++nt)
      acc2[nt] = mfma16(a2, bfragT(W2T + (size_t)(nt * 16) * 256 + kt * 32, 256, lane), acc2[nt]);
  }
  if (!active) return;
  int crow = r0 + lr;
#pragma unroll
  for (int nt = 0; nt < 8; ++nt){
    int col = nt * 16 + ccol;
    float bb = b2[col], sc = c1s[col], sb = c1b[col];
#pragma unroll
    for (int r = 0; r < 4; ++r){
      size_t idx = (size_t)(crow + r) * DM + col;
      float xres = h2[idx] * sc + sb;
      t[idx] = acc2[nt][r] + bb + xres;
    }
  }
}

// ---------------- host ----------------
extern "C" void kernel_launch(void* const* d_in, const int* in_sizes, int n_in,
                              void* d_out, int out_size, void* d_ws, size_t ws_size,
                              hipStream_t stream)
{
  const float* h    = (const float*)d_in[0];
  const float* e    = (const float*)d_in[2];
  const float* Wq   = (const float*)d_in[3];
  const float* Wk   = (const float*)d_in[4];
  const float* We   = (const float*)d_in[5];
  const float* Wv   = (const float*)d_in[6];
  const float* Wo   = (const float*)d_in[7];
  const float* bo   = (const float*)d_in[8];
  const float* bn1g = (const float*)d_in[9];
  const float* bn1b = (const float*)d_in[10];
  const float* bn2g = (const float*)d_in[11];
  const float* bn2b = (const float*)d_in[12];
  const float* W1   = (const float*)d_in[13];
  const float* b1   = (const float*)d_in[14];
  const float* W2   = (const float*)d_in[15];
  const float* b2   = (const float*)d_in[16];
  const int*   src  = (const int*)d_in[17];
  const int*   dst  = (const int*)d_in[18];

  int N = in_sizes[0] / DM;
  int E = in_sizes[2] / DM;
  float* out = (float*)d_out;

  char* ws = (char*)d_ws;
  size_t off_b = 0;
  auto alloc = [&](size_t bytes) -> char* {
    char* r = ws + off_b;
    off_b += (bytes + 255) & ~(size_t)255;
    return r;
  };
  __bf16* Qb    = (__bf16*)alloc((size_t)N * DM * 2);
  __bf16* Kb    = (__bf16*)alloc((size_t)N * DM * 2);
  __bf16* Vb    = (__bf16*)alloc((size_t)N * DM * 2);
  __bf16* hattn = (__bf16*)alloc((size_t)N * DM * 2);
  float* h2    = (float*)alloc((size_t)N * DM * 4);
  int*   deg    = (int*)alloc((size_t)N * 4);
  int*   offs   = (int*)alloc((size_t)N * 4);
  int*   cursor = (int*)alloc((size_t)N * 4);
  int*   sSrc   = (int*)alloc((size_t)E * 4);
  float* sS     = (float*)alloc((size_t)E * NH * 4);
  float* stats = (float*)alloc(1024 * 4);   // s1a s2a s1b s2b c1s c1b c2s c2b
  float* s1a = stats, *s2a = stats + 128, *s1b = stats + 256, *s2b = stats + 384;
  float* c1s = stats + 512, *c1b = stats + 640, *c2s = stats + 768, *c2b = stats + 896;
  __bf16* WqT = (__bf16*)alloc(16384 * 2);
  __bf16* WkT = (__bf16*)alloc(16384 * 2);
  __bf16* WvT = (__bf16*)alloc(16384 * 2);
  __bf16* WeT = (__bf16*)alloc(16384 * 2);
  __bf16* WoT = (__bf16*)alloc(16384 * 2);
  __bf16* W1T = (__bf16*)alloc(32768 * 2);
  __bf16* W2T = (__bf16*)alloc(32768 * 2);

  hipMemsetAsync(deg, 0, (size_t)N * 4, stream);
  hipMemsetAsync(stats, 0, 512 * 4, stream);

  k_transpose<<<64, 256, 0, stream>>>(Wq, WqT, DM, DM);
  k_transpose<<<64, 256, 0, stream>>>(Wk, WkT, DM, DM);
  k_transpose<<<64, 256, 0, stream>>>(Wv, WvT, DM, DM);
  k_transpose<<<64, 256, 0, stream>>>(We, WeT, DM, DM);
  k_transpose<<<64, 256, 0, stream>>>(Wo, WoT, DM, DM);
  k_transpose<<<128, 256, 0, stream>>>(W1, W1T, DM, 256);
  k_transpose<<<128, 256, 0, stream>>>(W2, W2T, 256, DM);

  k_hist<<<(E + 255) / 256, 256, 0, stream>>>(dst, deg, E);
  k_scan<<<1, 1024, 0, stream>>>(deg, offs, cursor, N);

  int rowblocks = (N / 16 + 3) / 4;
  k_qkv<<<rowblocks, 256, 0, stream>>>(h, WqT, WkT, WvT, Qb, Kb, Vb, N);
  k_edge<<<(E + 63) / 64, 256, 0, stream>>>(e, WeT, Qb, Kb, src, dst, cursor, sSrc, sS, E);
  k_gather<<<(N + 7) / 8, 256, 0, stream>>>(offs, cursor, sSrc, sS, Vb, hattn, N);
  k_attnout<<<rowblocks, 256, 0, stream>>>(hattn, h, WoT, bo, h2, N);
  k_bnstats<<<256, 256, 0, stream>>>(h2, s1a, s2a, N);
  k_bncoef<<<1, 128, 0, stream>>>(s1a, s2a, bn1g, bn1b, c1s, c1b, N);
  k_ffn<<<rowblocks, 256, 0, stream>>>(h2, c1s, c1b, W1T, b1, W2T, b2, out, N);
  k_bnstats<<<256, 256, 0, stream>>>(out, s1b, s2b, N);
  k_bncoef<<<1, 128, 0, stream>>>(s1b, s2b, bn2g, bn2b, c2s, c2b, N);
  long long total4 = (long long)N * DM / 4;
  k_bnapply<<<(int)((total4 + 255) / 256), 256, 0, stream>>>(out, c2s, c2b, total4);
}

// Round 5
// 671.793 us; speedup vs baseline: 1.2576x; 1.1317x over previous
//
#include <hip/hip_runtime.h>

#define DM 128
#define NH 8
#define DH 16

typedef __bf16 bf8 __attribute__((ext_vector_type(8)));
typedef __bf16 bf4 __attribute__((ext_vector_type(4)));
typedef float  f4  __attribute__((ext_vector_type(4)));

__device__ __forceinline__ f4 mfma16(bf8 a, bf8 b, f4 c){
  return __builtin_amdgcn_mfma_f32_16x16x32_bf16(a, b, c, 0, 0, 0);
}

// B fragment from pre-transposed bf16 weight WT[out][k]; ptr must be at (col0,k0)
__device__ __forceinline__ bf8 bfragT(const __bf16* __restrict__ WT, int ldk, int lane){
  const __bf16* p = WT + (size_t)(lane & 15) * ldk + ((lane >> 4) << 3);
  return *(const bf8*)p;
}

// convert 8 contiguous fp32 -> bf16x8 fragment
__device__ __forceinline__ bf8 cvt8(const float* __restrict__ p){
  f4 u = *(const f4*)p;
  f4 v = *(const f4*)(p + 4);
  bf8 r;
  r[0]=(__bf16)u[0]; r[1]=(__bf16)u[1]; r[2]=(__bf16)u[2]; r[3]=(__bf16)u[3];
  r[4]=(__bf16)v[0]; r[5]=(__bf16)v[1]; r[6]=(__bf16)v[2]; r[7]=(__bf16)v[3];
  return r;
}

// ---------------- all weight transposes in one launch ----------------
__global__ __launch_bounds__(256) void k_prep(const float* __restrict__ Wq,
    const float* __restrict__ Wk, const float* __restrict__ Wv,
    const float* __restrict__ We, const float* __restrict__ Wo,
    const float* __restrict__ W1, const float* __restrict__ W2,
    __bf16* __restrict__ WqT, __bf16* __restrict__ WkT, __bf16* __restrict__ WvT,
    __bf16* __restrict__ WeT, __bf16* __restrict__ WoT,
    __bf16* __restrict__ W1T, __bf16* __restrict__ W2T)
{
  int b = blockIdx.x;
  const float* W; __bf16* T; int K, M, idx;
  if (b < 320){
    int w = b >> 6;
    W = w==0?Wq: w==1?Wk: w==2?Wv: w==3?We: Wo;
    T = w==0?WqT: w==1?WkT: w==2?WvT: w==3?WeT: WoT;
    K = 128; M = 128; idx = (b & 63) * 256 + threadIdx.x;
  } else if (b < 448){
    W = W1; T = W1T; K = 128; M = 256; idx = (b - 320) * 256 + threadIdx.x;
  } else {
    W = W2; T = W2T; K = 256; M = 128; idx = (b - 448) * 256 + threadIdx.x;
  }
  int m = idx / K, k = idx - m * K;
  T[idx] = (__bf16)W[(size_t)k * M + m];
}

// ---------------- CSR build ----------------
__global__ void k_hist(const int* __restrict__ dst, int* __restrict__ deg, int E){
  int i = blockIdx.x * 256 + threadIdx.x;
  if (i < E) atomicAdd(&deg[dst[i]], 1);
}

__global__ __launch_bounds__(1024) void k_scan(const int* __restrict__ deg,
    int* __restrict__ off, int* __restrict__ cursor, int N)
{
  __shared__ int part[1024];
  int t = threadIdx.x;
  int C = (N + 1023) >> 10;
  int base = t * C;
  int sum = 0;
  for (int i = 0; i < C; ++i){ int idx = base + i; if (idx < N) sum += deg[idx]; }
  part[t] = sum;
  __syncthreads();
  for (int d = 1; d < 1024; d <<= 1){
    int add = (t >= d) ? part[t - d] : 0;
    __syncthreads();
    part[t] += add;
    __syncthreads();
  }
  int run = (t == 0) ? 0 : part[t - 1];
  for (int i = 0; i < C; ++i){
    int idx = base + i;
    if (idx < N){ off[idx] = run; cursor[idx] = run; run += deg[idx]; }
  }
}

// ---------------- K1: Q,K,V = h @ Wq/Wk/Wv  (bf16 outputs) ----------------
__global__ __launch_bounds__(256) void k_qkv(const float* __restrict__ h,
    const __bf16* __restrict__ WqT, const __bf16* __restrict__ WkT, const __bf16* __restrict__ WvT,
    __bf16* __restrict__ Q, __bf16* __restrict__ K, __bf16* __restrict__ V, int N)
{
  int lane = threadIdx.x & 63;
  int r0 = (blockIdx.x * 4 + (threadIdx.x >> 6)) * 16;
  if (r0 + 16 > N) return;
  bf8 a[4];
  int arow = r0 + (lane & 15);
  int koff = (lane >> 4) << 3;
#pragma unroll
  for (int kt = 0; kt < 4; ++kt)
    a[kt] = cvt8(h + (size_t)arow * DM + kt * 32 + koff);

  const __bf16* Ws[3] = {WqT, WkT, WvT};
  __bf16* Os[3] = {Q, K, V};
  int crow = r0 + ((lane >> 4) << 2);
  int ccol = lane & 15;
#pragma unroll
  for (int o = 0; o < 3; ++o){
#pragma unroll
    for (int nt = 0; nt < 8; ++nt){
      f4 acc = {0.f, 0.f, 0.f, 0.f};
#pragma unroll
      for (int kt = 0; kt < 4; ++kt)
        acc = mfma16(a[kt], bfragT(Ws[o] + (size_t)(nt * 16) * DM + kt * 32, DM, lane), acc);
      __bf16* outp = Os[o] + (size_t)crow * DM + nt * 16 + ccol;
      outp[0] = (__bf16)acc[0]; outp[DM] = (__bf16)acc[1];
      outp[2 * DM] = (__bf16)acc[2]; outp[3 * DM] = (__bf16)acc[3];
    }
  }
}

// ---------------- K2: fused Eh GEMM + edge scoring ----------------
// Each wave owns 16 edges and its own 16 Eh rows: NO __syncthreads.
// Gathers pre-issued before/around the MFMA block to hide LLC latency.
__global__ __launch_bounds__(256) void k_edge(const float* __restrict__ e,
    const __bf16* __restrict__ WeT,
    const __bf16* __restrict__ Qb, const __bf16* __restrict__ Kb,
    const int* __restrict__ src, const int* __restrict__ dst,
    int* __restrict__ cursor, int* __restrict__ sSrc, float* __restrict__ sS, int E)
{
  __shared__ __bf16 Eh[64][132];
  int tid = threadIdx.x, lane = tid & 63, wave = tid >> 6;
  int e0 = blockIdx.x * 64 + wave * 16;     // this wave's 16 edges
  // edge meta (lanes 0..15 of each wave)
  int ei = e0 + (lane & 15);
  bool vmeta = (lane < 16) && (ei < E);
  int sv = 0, dv = 0, slotv = 0;
  if (vmeta){ sv = src[ei]; dv = dst[ei]; }
  // e-row loads (issue early)
  int er = min(e0 + (lane & 15), E - 1);
  int koff = (lane >> 4) << 3;
  f4 eu[4], ew[4];
#pragma unroll
  for (int kt = 0; kt < 4; ++kt){
    const float* p = e + (size_t)er * DM + kt * 32 + koff;
    eu[kt] = *(const f4*)p; ew[kt] = *(const f4*)(p + 4);
  }
  // CSR slot alloc (atomic latency hides under GEMM)
  if (vmeta){ slotv = atomicAdd(&cursor[dv], 1); sSrc[slotv] = sv; }
  // broadcast src/dst for this half-wave's 8 edges
  int half = lane >> 5, l32 = lane & 31, hh = l32 >> 2;
  int jsrc[8], jdst[8];
#pragma unroll
  for (int i = 0; i < 8; ++i){
    jsrc[i] = __shfl(sv, i * 2 + half, 64);
    jdst[i] = __shfl(dv, i * 2 + half, 64);
  }
  // group-0 gathers (edges 0..3): in flight across the whole MFMA block
  bf4 kr[4], qr[4];
#pragma unroll
  for (int q = 0; q < 4; ++q){
    kr[q] = *(const bf4*)(Kb + (size_t)jsrc[q] * DM + l32 * 4);
    qr[q] = *(const bf4*)(Qb + (size_t)jdst[q] * DM + l32 * 4);
  }
  // A fragments
  bf8 a[4];
#pragma unroll
  for (int kt = 0; kt < 4; ++kt){
    bf8 r;
    r[0]=(__bf16)eu[kt][0]; r[1]=(__bf16)eu[kt][1]; r[2]=(__bf16)eu[kt][2]; r[3]=(__bf16)eu[kt][3];
    r[4]=(__bf16)ew[kt][0]; r[5]=(__bf16)ew[kt][1]; r[6]=(__bf16)ew[kt][2]; r[7]=(__bf16)ew[kt][3];
    a[kt] = r;
  }
  int lrow = (lane >> 4) << 2;
  int ccol = lane & 15;
  int wrow = wave * 16;
#pragma unroll
  for (int nt = 0; nt < 8; ++nt){
    f4 acc = {0.f, 0.f, 0.f, 0.f};
#pragma unroll
    for (int kt = 0; kt < 4; ++kt)
      acc = mfma16(a[kt], bfragT(WeT + (size_t)(nt * 16) * DM + kt * 32, DM, lane), acc);
    int col = nt * 16 + ccol;
#pragma unroll
    for (int r = 0; r < 4; ++r) Eh[wrow + lrow + r][col] = (__bf16)acc[r];
  }
  // group-1 gathers (edges 4..7) issued before group-0 is consumed
  bf4 kn[4], qn[4];
#pragma unroll
  for (int q = 0; q < 4; ++q){
    kn[q] = *(const bf4*)(Kb + (size_t)jsrc[q + 4] * DM + l32 * 4);
    qn[q] = *(const bf4*)(Qb + (size_t)jdst[q + 4] * DM + l32 * 4);
  }
  int jslot[8];
#pragma unroll
  for (int i = 0; i < 8; ++i) jslot[i] = __shfl(slotv, i * 2 + half, 64);
  // consume (within-wave LDS dependency only: no barrier)
#pragma unroll
  for (int q = 0; q < 8; ++q){
    bf4 kv = (q < 4) ? kr[q] : kn[q - 4];
    bf4 qv = (q < 4) ? qr[q] : qn[q - 4];
    int j = wrow + q * 2 + half;
    bf4 evv = *(const bf4*)&Eh[j][l32 * 4];
    float dsum = (float)kv[0]*(float)qv[0]*(float)evv[0]
               + (float)kv[1]*(float)qv[1]*(float)evv[1]
               + (float)kv[2]*(float)qv[2]*(float)evv[2]
               + (float)kv[3]*(float)qv[3]*(float)evv[3];
    dsum += __shfl_xor(dsum, 1);
    dsum += __shfl_xor(dsum, 2);
    if (((l32 & 3) == 0) && (e0 + q * 2 + half) < E){
      float dd = fminf(5.f, fmaxf(-5.f, dsum * 0.25f));
      sS[(size_t)jslot[q] * NH + hh] = __expf(dd);
    }
  }
}

// ---------------- K2c: per-node gather reduction (32 lanes/node, 4-wide rounds) ----------------
__global__ __launch_bounds__(256) void k_gather(const int* __restrict__ off,
    const int* __restrict__ cend, const int* __restrict__ sSrc, const float* __restrict__ sS,
    const __bf16* __restrict__ Vb, __bf16* __restrict__ hattn, int N)
{
  int lane = threadIdx.x & 63;
  int half = lane >> 5, l32 = lane & 31;
  int node = blockIdx.x * 8 + (threadIdx.x >> 6) * 2 + half;
  if (node >= N) return;
  int start = off[node], end = cend[node];
  int hh = l32 >> 2;
  float a0 = 0.f, a1 = 0.f, a2 = 0.f, a3 = 0.f, z = 0.f;
  if (end > start){
    int idx[4], sj[4];
#pragma unroll
    for (int q = 0; q < 4; ++q) idx[q] = (start + q < end) ? start + q : end - 1;
#pragma unroll
    for (int q = 0; q < 4; ++q) sj[q] = sSrc[idx[q]];
    for (int base = start; base < end; base += 4){
      int nbase = base + 4;
      bool more = nbase < end;
      int nidx[4], nsj[4];
#pragma unroll
      for (int q = 0; q < 4; ++q) nidx[q] = (nbase + q < end) ? nbase + q : end - 1;
      if (more){
#pragma unroll
        for (int q = 0; q < 4; ++q) nsj[q] = sSrc[nidx[q]];
      }
      float s[4]; bf4 v[4];
#pragma unroll
      for (int q = 0; q < 4; ++q)
        s[q] = (base + q < end) ? sS[(size_t)idx[q] * NH + hh] : 0.f;
#pragma unroll
      for (int q = 0; q < 4; ++q)
        v[q] = *(const bf4*)(Vb + (size_t)sj[q] * DM + l32 * 4);
#pragma unroll
      for (int q = 0; q < 4; ++q){
        a0 += s[q] * (float)v[q][0]; a1 += s[q] * (float)v[q][1];
        a2 += s[q] * (float)v[q][2]; a3 += s[q] * (float)v[q][3];
        z += s[q];
      }
#pragma unroll
      for (int q = 0; q < 4; ++q){ idx[q] = nidx[q]; if (more) sj[q] = nsj[q]; }
    }
  }
  float invz = 1.f / (z + 1e-6f);
  bf4 o;
  o[0] = (__bf16)(a0 * invz); o[1] = (__bf16)(a1 * invz);
  o[2] = (__bf16)(a2 * invz); o[3] = (__bf16)(a3 * invz);
  *(bf4*)(hattn + (size_t)node * DM + l32 * 4) = o;
}

// ---------------- K3: h2 = h + h_attn @ Wo + bo  (bf16 out) + fused BN1 stats ----------------
__global__ __launch_bounds__(256) void k_attnout(const __bf16* __restrict__ hattn,
    const float* __restrict__ h,
    const __bf16* __restrict__ WoT, const float* __restrict__ bo,
    __bf16* __restrict__ h2, float* __restrict__ s1, float* __restrict__ s2, int N)
{
  __shared__ float ls[256];     // [0..127]=sum, [128..255]=sumsq
  int tid = threadIdx.x;
  ls[tid] = 0.f;
  __syncthreads();
  int lane = tid & 63;
  int r0 = (blockIdx.x * 4 + (tid >> 6)) * 16;
  bool active = (r0 + 16 <= N);
  int r0c = active ? r0 : 0;
  int arow = r0c + (lane & 15);
  int kof = (lane >> 4) << 3;
  bf8 a[4];
#pragma unroll
  for (int kt = 0; kt < 4; ++kt)
    a[kt] = *(const bf8*)(hattn + (size_t)arow * DM + kt * 32 + kof);
  int crow = r0c + ((lane >> 4) << 2);
  int ccol = lane & 15;
#pragma unroll
  for (int nt = 0; nt < 8; ++nt){
    f4 acc = {0.f, 0.f, 0.f, 0.f};
#pragma unroll
    for (int kt = 0; kt < 4; ++kt)
      acc = mfma16(a[kt], bfragT(WoT + (size_t)(nt * 16) * DM + kt * 32, DM, lane), acc);
    int col = nt * 16 + ccol;
    float bb = bo[col];
    if (active){
      float p1 = 0.f, p2 = 0.f;
#pragma unroll
      for (int r = 0; r < 4; ++r){
        size_t idx = (size_t)(crow + r) * DM + col;
        float v = h[idx] + acc[r] + bb;
        h2[idx] = (__bf16)v;
        p1 += v; p2 += v * v;
      }
      atomicAdd(&ls[col], p1);
      atomicAdd(&ls[128 + col], p2);
    }
  }
  __syncthreads();
  if (tid < 128){
    atomicAdd(&s1[tid], ls[tid]);
    atomicAdd(&s2[tid], ls[128 + tid]);
  }
}

__global__ void k_bncoef(const float* __restrict__ s1, const float* __restrict__ s2,
    const float* __restrict__ gam, const float* __restrict__ bet,
    float* __restrict__ cs, float* __restrict__ cb, int N)
{
  int c = threadIdx.x;
  if (c >= DM) return;
  float mean = s1[c] / (float)N;
  float var  = s2[c] / (float)N - mean * mean;
  float rs   = rsqrtf(var + 1e-5f);
  float sc   = gam[c] * rs;
  cs[c] = sc;
  cb[c] = bet[c] - mean * sc;
}

__global__ void k_bnapply(float* __restrict__ t, const float* __restrict__ cs,
    const float* __restrict__ cb, long long total4)
{
  long long i = (long long)blockIdx.x * blockDim.x + threadIdx.x;
  if (i >= total4) return;
  f4* p = (f4*)t + i;
  f4 v = *p;
  int c = (int)((i * 4) & (DM - 1));
  v[0] = v[0] * cs[c]     + cb[c];
  v[1] = v[1] * cs[c + 1] + cb[c + 1];
  v[2] = v[2] * cs[c + 2] + cb[c + 2];
  v[3] = v[3] * cs[c + 3] + cb[c + 3];
  *p = v;
}

// ---------------- K6: FFN fused (x=BN1(h2); t = x + relu(x@W1+b1)@W2 + b2) + BN2 stats ----------------
__global__ __launch_bounds__(256) void k_ffn(const __bf16* __restrict__ h2,
    const float* __restrict__ c1s, const float* __restrict__ c1b,
    const __bf16* __restrict__ W1T, const float* __restrict__ b1,
    const __bf16* __restrict__ W2T, const float* __restrict__ b2,
    float* __restrict__ t, float* __restrict__ s1, float* __restrict__ s2, int N)
{
  __shared__ __bf16 hid[4][16][256];   // 32 KiB
  __shared__ float ls[256];
  int tid = threadIdx.x;
  ls[tid] = 0.f;
  int lane = tid & 63, wave = tid >> 6;
  int r0 = (blockIdx.x * 4 + wave) * 16;
  bool active = (r0 + 16 <= N);
  int r0c = active ? r0 : 0;

  int arow = r0c + (lane & 15);
  int kof = (lane >> 4) << 3;
  bf8 a[4];
#pragma unroll
  for (int kt = 0; kt < 4; ++kt){
    int kb = kt * 32 + kof;
    bf8 hv = *(const bf8*)(h2 + (size_t)arow * DM + kb);
    const f4* ps = (const f4*)(c1s + kb);
    const f4* pb = (const f4*)(c1b + kb);
    f4 s0 = ps[0], s1v = ps[1], b0 = pb[0], b1v = pb[1];
    bf8 r;
    r[0]=(__bf16)((float)hv[0]*s0[0]+b0[0]); r[1]=(__bf16)((float)hv[1]*s0[1]+b0[1]);
    r[2]=(__bf16)((float)hv[2]*s0[2]+b0[2]); r[3]=(__bf16)((float)hv[3]*s0[3]+b0[3]);
    r[4]=(__bf16)((float)hv[4]*s1v[0]+b1v[0]); r[5]=(__bf16)((float)hv[5]*s1v[1]+b1v[1]);
    r[6]=(__bf16)((float)hv[6]*s1v[2]+b1v[2]); r[7]=(__bf16)((float)hv[7]*s1v[3]+b1v[3]);
    a[kt] = r;
  }
  int lr = (lane >> 4) << 2;
  int ccol = lane & 15;
  // GEMM1: 16x256, relu -> LDS (bf16)
#pragma unroll
  for (int nt = 0; nt < 16; ++nt){
    f4 acc = {0.f, 0.f, 0.f, 0.f};
#pragma unroll
    for (int kt = 0; kt < 4; ++kt)
      acc = mfma16(a[kt], bfragT(W1T + (size_t)(nt * 16) * DM + kt * 32, DM, lane), acc);
    int col = nt * 16 + ccol;
    float bb = b1[col];
#pragma unroll
    for (int r = 0; r < 4; ++r)
      hid[wave][lr + r][col] = (__bf16)fmaxf(acc[r] + bb, 0.f);
  }
  __syncthreads();
  // GEMM2: 16x128, K=256
  f4 acc2[8];
#pragma unroll
  for (int nt = 0; nt < 8; ++nt){ acc2[nt][0]=0.f; acc2[nt][1]=0.f; acc2[nt][2]=0.f; acc2[nt][3]=0.f; }
#pragma unroll
  for (int kt = 0; kt < 8; ++kt){
    bf8 a2 = *(const bf8*)&hid[wave][lane & 15][kt * 32 + kof];
#pragma unroll
    for (int nt = 0; nt < 8; ++nt)
      acc2[nt] = mfma16(a2, bfragT(W2T + (size_t)(nt * 16) * 256 + kt * 32, 256, lane), acc2[nt]);
  }
  int crow = r0c + lr;
#pragma unroll
  for (int nt = 0; nt < 8; ++nt){
    int col = nt * 16 + ccol;
    float bb = b2[col], sc = c1s[col], sb = c1b[col];
    if (active){
      float p1 = 0.f, p2 = 0.f;
#pragma unroll
      for (int r = 0; r < 4; ++r){
        size_t idx = (size_t)(crow + r) * DM + col;
        float xres = (float)h2[idx] * sc + sb;
        float v = acc2[nt][r] + bb + xres;
        t[idx] = v;
        p1 += v; p2 += v * v;
      }
      atomicAdd(&ls[col], p1);
      atomicAdd(&ls[128 + col], p2);
    }
  }
  __syncthreads();
  if (tid < 128){
    atomicAdd(&s1[tid], ls[tid]);
    atomicAdd(&s2[tid], ls[128 + tid]);
  }
}

// ---------------- host ----------------
extern "C" void kernel_launch(void* const* d_in, const int* in_sizes, int n_in,
                              void* d_out, int out_size, void* d_ws, size_t ws_size,
                              hipStream_t stream)
{
  const float* h    = (const float*)d_in[0];
  const float* e    = (const float*)d_in[2];
  const float* Wq   = (const float*)d_in[3];
  const float* Wk   = (const float*)d_in[4];
  const float* We   = (const float*)d_in[5];
  const float* Wv   = (const float*)d_in[6];
  const float* Wo   = (const float*)d_in[7];
  const float* bo   = (const float*)d_in[8];
  const float* bn1g = (const float*)d_in[9];
  const float* bn1b = (const float*)d_in[10];
  const float* bn2g = (const float*)d_in[11];
  const float* bn2b = (const float*)d_in[12];
  const float* W1   = (const float*)d_in[13];
  const float* b1   = (const float*)d_in[14];
  const float* W2   = (const float*)d_in[15];
  const float* b2   = (const float*)d_in[16];
  const int*   src  = (const int*)d_in[17];
  const int*   dst  = (const int*)d_in[18];

  int N = in_sizes[0] / DM;
  int E = in_sizes[2] / DM;
  float* out = (float*)d_out;

  char* ws = (char*)d_ws;
  size_t off_b = 0;
  auto alloc = [&](size_t bytes) -> char* {
    char* r = ws + off_b;
    off_b += (bytes + 255) & ~(size_t)255;
    return r;
  };
  __bf16* Qb    = (__bf16*)alloc((size_t)N * DM * 2);
  __bf16* Kb    = (__bf16*)alloc((size_t)N * DM * 2);
  __bf16* Vb    = (__bf16*)alloc((size_t)N * DM * 2);
  __bf16* hattn = (__bf16*)alloc((size_t)N * DM * 2);
  __bf16* h2    = (__bf16*)alloc((size_t)N * DM * 2);
  int*   deg    = (int*)alloc((size_t)N * 4);
  int*   offs   = (int*)alloc((size_t)N * 4);
  int*   cursor = (int*)alloc((size_t)N * 4);
  int*   sSrc   = (int*)alloc((size_t)E * 4);
  float* sS     = (float*)alloc((size_t)E * NH * 4);
  float* stats = (float*)alloc(1024 * 4);   // s1a s2a s1b s2b c1s c1b c2s c2b
  float* s1a = stats, *s2a = stats + 128, *s1b = stats + 256, *s2b = stats + 384;
  float* c1s = stats + 512, *c1b = stats + 640, *c2s = stats + 768, *c2b = stats + 896;
  __bf16* WqT = (__bf16*)alloc(16384 * 2);
  __bf16* WkT = (__bf16*)alloc(16384 * 2);
  __bf16* WvT = (__bf16*)alloc(16384 * 2);
  __bf16* WeT = (__bf16*)alloc(16384 * 2);
  __bf16* WoT = (__bf16*)alloc(16384 * 2);
  __bf16* W1T = (__bf16*)alloc(32768 * 2);
  __bf16* W2T = (__bf16*)alloc(32768 * 2);

  hipMemsetAsync(deg, 0, (size_t)N * 4, stream);
  hipMemsetAsync(stats, 0, 512 * 4, stream);

  k_prep<<<576, 256, 0, stream>>>(Wq, Wk, Wv, We, Wo, W1, W2,
                                  WqT, WkT, WvT, WeT, WoT, W1T, W2T);
  k_hist<<<(E + 255) / 256, 256, 0, stream>>>(dst, deg, E);
  k_scan<<<1, 1024, 0, stream>>>(deg, offs, cursor, N);

  int rowblocks = (N / 16 + 3) / 4;
  k_qkv<<<rowblocks, 256, 0, stream>>>(h, WqT, WkT, WvT, Qb, Kb, Vb, N);
  k_edge<<<(E + 63) / 64, 256, 0, stream>>>(e, WeT, Qb, Kb, src, dst, cursor, sSrc, sS, E);
  k_gather<<<(N + 7) / 8, 256, 0, stream>>>(offs, cursor, sSrc, sS, Vb, hattn, N);
  k_attnout<<<rowblocks, 256, 0, stream>>>(hattn, h, WoT, bo, h2, s1a, s2a, N);
  k_bncoef<<<1, 128, 0, stream>>>(s1a, s2a, bn1g, bn1b, c1s, c1b, N);
  k_ffn<<<rowblocks, 256, 0, stream>>>(h2, c1s, c1b, W1T, b1, W2T, b2, out, s1b, s2b, N);
  k_bncoef<<<1, 128, 0, stream>>>(s1b, s2b, bn2g, bn2b, c2s, c2b, N);
  long long total4 = (long long)N * DM / 4;
  k_bnapply<<<(int)((total4 + 255) / 256), 256, 0, stream>>>(out, c2s, c2b, total4);
}

// Round 6
// 574.104 us; speedup vs baseline: 1.4716x; 1.1702x over previous
//
#include <hip/hip_runtime.h>

#define DM 128
#define NH 8
#define DH 16

typedef __bf16 bf8 __attribute__((ext_vector_type(8)));
typedef __bf16 bf4 __attribute__((ext_vector_type(4)));
typedef float  f4  __attribute__((ext_vector_type(4)));

__device__ __forceinline__ f4 mfma16(bf8 a, bf8 b, f4 c){
  return __builtin_amdgcn_mfma_f32_16x16x32_bf16(a, b, c, 0, 0, 0);
}

// B fragment from pre-transposed bf16 weight WT[out][k]; ptr must be at (col0,k0)
__device__ __forceinline__ bf8 bfragT(const __bf16* __restrict__ WT, int ldk, int lane){
  const __bf16* p = WT + (size_t)(lane & 15) * ldk + ((lane >> 4) << 3);
  return *(const bf8*)p;
}

// convert 8 contiguous fp32 -> bf16x8 fragment
__device__ __forceinline__ bf8 cvt8(const float* __restrict__ p){
  f4 u = *(const f4*)p;
  f4 v = *(const f4*)(p + 4);
  bf8 r;
  r[0]=(__bf16)u[0]; r[1]=(__bf16)u[1]; r[2]=(__bf16)u[2]; r[3]=(__bf16)u[3];
  r[4]=(__bf16)v[0]; r[5]=(__bf16)v[1]; r[6]=(__bf16)v[2]; r[7]=(__bf16)v[3];
  return r;
}

// ---------------- all weight transposes in one launch ----------------
__global__ __launch_bounds__(256) void k_prep(const float* __restrict__ Wq,
    const float* __restrict__ Wk, const float* __restrict__ Wv,
    const float* __restrict__ We, const float* __restrict__ Wo,
    const float* __restrict__ W1, const float* __restrict__ W2,
    __bf16* __restrict__ WqT, __bf16* __restrict__ WkT, __bf16* __restrict__ WvT,
    __bf16* __restrict__ WeT, __bf16* __restrict__ WoT,
    __bf16* __restrict__ W1T, __bf16* __restrict__ W2T)
{
  int b = blockIdx.x;
  const float* W; __bf16* T; int K, M, idx;
  if (b < 320){
    int w = b >> 6;
    W = w==0?Wq: w==1?Wk: w==2?Wv: w==3?We: Wo;
    T = w==0?WqT: w==1?WkT: w==2?WvT: w==3?WeT: WoT;
    K = 128; M = 128; idx = (b & 63) * 256 + threadIdx.x;
  } else if (b < 448){
    W = W1; T = W1T; K = 128; M = 256; idx = (b - 320) * 256 + threadIdx.x;
  } else {
    W = W2; T = W2T; K = 256; M = 128; idx = (b - 448) * 256 + threadIdx.x;
  }
  int m = idx / K, k = idx - m * K;
  T[idx] = (__bf16)W[(size_t)k * M + m];
}

// ---------------- CSR build ----------------
__global__ void k_hist(const int* __restrict__ dst, int* __restrict__ deg, int E){
  int i = blockIdx.x * 256 + threadIdx.x;
  if (i < E) atomicAdd(&deg[dst[i]], 1);
}

__global__ __launch_bounds__(1024) void k_scan(const int* __restrict__ deg,
    int* __restrict__ off, int* __restrict__ cursor, int N)
{
  __shared__ int part[1024];
  int t = threadIdx.x;
  int C = (N + 1023) >> 10;
  int base = t * C;
  int sum = 0;
  for (int i = 0; i < C; ++i){ int idx = base + i; if (idx < N) sum += deg[idx]; }
  part[t] = sum;
  __syncthreads();
  for (int d = 1; d < 1024; d <<= 1){
    int add = (t >= d) ? part[t - d] : 0;
    __syncthreads();
    part[t] += add;
    __syncthreads();
  }
  int run = (t == 0) ? 0 : part[t - 1];
  for (int i = 0; i < C; ++i){
    int idx = base + i;
    if (idx < N){ off[idx] = run; cursor[idx] = run; run += deg[idx]; }
  }
}

// ---------------- K1: Q,K,V = h @ Wq/Wk/Wv  (bf16 outputs) ----------------
__global__ __launch_bounds__(256) void k_qkv(const float* __restrict__ h,
    const __bf16* __restrict__ WqT, const __bf16* __restrict__ WkT, const __bf16* __restrict__ WvT,
    __bf16* __restrict__ Q, __bf16* __restrict__ K, __bf16* __restrict__ V, int N)
{
  int lane = threadIdx.x & 63;
  int r0 = (blockIdx.x * 4 + (threadIdx.x >> 6)) * 16;
  if (r0 + 16 > N) return;
  bf8 a[4];
  int arow = r0 + (lane & 15);
  int koff = (lane >> 4) << 3;
#pragma unroll
  for (int kt = 0; kt < 4; ++kt)
    a[kt] = cvt8(h + (size_t)arow * DM + kt * 32 + koff);

  const __bf16* Ws[3] = {WqT, WkT, WvT};
  __bf16* Os[3] = {Q, K, V};
  int crow = r0 + ((lane >> 4) << 2);
  int ccol = lane & 15;
#pragma unroll
  for (int o = 0; o < 3; ++o){
#pragma unroll
    for (int nt = 0; nt < 8; ++nt){
      f4 acc = {0.f, 0.f, 0.f, 0.f};
#pragma unroll
      for (int kt = 0; kt < 4; ++kt)
        acc = mfma16(a[kt], bfragT(Ws[o] + (size_t)(nt * 16) * DM + kt * 32, DM, lane), acc);
      __bf16* outp = Os[o] + (size_t)crow * DM + nt * 16 + ccol;
      outp[0] = (__bf16)acc[0]; outp[DM] = (__bf16)acc[1];
      outp[2 * DM] = (__bf16)acc[2]; outp[3 * DM] = (__bf16)acc[3];
    }
  }
}

// ---------------- K2: persistent pipelined Eh GEMM + edge scoring ----------------
// Each wave owns a strided sequence of 16-edge tiles; no __syncthreads anywhere.
// While tile t is consumed, tile t+1's meta/e-rows/gathers are already in flight.
__global__ __launch_bounds__(256) void k_edge(const float* __restrict__ e,
    const __bf16* __restrict__ WeT,
    const __bf16* __restrict__ Qb, const __bf16* __restrict__ Kb,
    const int* __restrict__ src, const int* __restrict__ dst,
    int* __restrict__ cursor, int* __restrict__ sSrc, float* __restrict__ sS,
    int E, int T, int NW)
{
  __shared__ __bf16 Eh[64][132];
  int tid = threadIdx.x, lane = tid & 63, wave = tid >> 6;
  int l16 = lane & 15;
  int koff = (lane >> 4) << 3;
  int half = lane >> 5, l32 = lane & 31, hh = l32 >> 2;
  int lrow = (lane >> 4) << 2;
  int wrow = wave * 16;
  int gw = blockIdx.x * 4 + wave;

  int t = gw;
  if (t >= T) return;

  // ---- prologue: stage tile t ----
  int ei = min(t * 16 + l16, E - 1);
  int sv = src[ei], dv = dst[ei];
  int slotv = 0;
  if ((lane < 16) && (t * 16 + l16 < E)){
    slotv = atomicAdd(&cursor[dv], 1);
    sSrc[slotv] = sv;
  }
  f4 eu[4], ew[4];
#pragma unroll
  for (int kt = 0; kt < 4; ++kt){
    const float* p = e + (size_t)ei * DM + kt * 32 + koff;
    eu[kt] = *(const f4*)p; ew[kt] = *(const f4*)(p + 4);
  }
  bf4 kr[8], qr[8];
#pragma unroll
  for (int i = 0; i < 8; ++i){
    int js = __shfl(sv, i * 2 + half, 64);
    int jd = __shfl(dv, i * 2 + half, 64);
    kr[i] = *(const bf4*)(Kb + (size_t)js * DM + l32 * 4);
    qr[i] = *(const bf4*)(Qb + (size_t)jd * DM + l32 * 4);
  }

  while (t < T){
    int tn = t + NW;
    bool has_next = (tn < T);
    // A fragments (consume eu/ew so they can be re-staged)
    bf8 a[4];
#pragma unroll
    for (int kt = 0; kt < 4; ++kt){
      bf8 r;
      r[0]=(__bf16)eu[kt][0]; r[1]=(__bf16)eu[kt][1]; r[2]=(__bf16)eu[kt][2]; r[3]=(__bf16)eu[kt][3];
      r[4]=(__bf16)ew[kt][0]; r[5]=(__bf16)ew[kt][1]; r[6]=(__bf16)ew[kt][2]; r[7]=(__bf16)ew[kt][3];
      a[kt] = r;
    }
    // issue meta loads for t+1 early
    int svn = 0, dvn = 0, slotn = 0;
    if (has_next){
      int ein = min(tn * 16 + l16, E - 1);
      svn = src[ein]; dvn = dst[ein];
    }
    // MFMA tile t -> wave-private Eh rows
#pragma unroll
    for (int nt = 0; nt < 8; ++nt){
      f4 acc = {0.f, 0.f, 0.f, 0.f};
#pragma unroll
      for (int kt = 0; kt < 4; ++kt)
        acc = mfma16(a[kt], bfragT(WeT + (size_t)(nt * 16) * DM + kt * 32, DM, lane), acc);
      int col = nt * 16 + l16;
#pragma unroll
      for (int r = 0; r < 4; ++r) Eh[wrow + lrow + r][col] = (__bf16)acc[r];
    }
    // stage tile t+1: e-rows + CSR slot (latency hides under consume below)
    if (has_next){
      int ern = min(tn * 16 + l16, E - 1);
#pragma unroll
      for (int kt = 0; kt < 4; ++kt){
        const float* p = e + (size_t)ern * DM + kt * 32 + koff;
        eu[kt] = *(const f4*)p; ew[kt] = *(const f4*)(p + 4);
      }
      if ((lane < 16) && (tn * 16 + l16 < E)){
        slotn = atomicAdd(&cursor[dvn], 1);
        sSrc[slotn] = svn;
      }
    }
    // consume tile t (kr/qr issued an iteration ago; Eh just written by this wave)
    int e0c = t * 16;
#pragma unroll
    for (int q = 0; q < 8; ++q){
      int jslot = __shfl(slotv, q * 2 + half, 64);
      bf4 evv = *(const bf4*)&Eh[wrow + q * 2 + half][l32 * 4];
      bf4 kv = kr[q], qv = qr[q];
      float dsum = (float)kv[0]*(float)qv[0]*(float)evv[0]
                 + (float)kv[1]*(float)qv[1]*(float)evv[1]
                 + (float)kv[2]*(float)qv[2]*(float)evv[2]
                 + (float)kv[3]*(float)qv[3]*(float)evv[3];
      dsum += __shfl_xor(dsum, 1);
      dsum += __shfl_xor(dsum, 2);
      if (((l32 & 3) == 0) && (e0c + q * 2 + half) < E){
        float dd = fminf(5.f, fmaxf(-5.f, dsum * 0.25f));
        sS[(size_t)jslot * NH + hh] = __expf(dd);
      }
    }
    // issue gathers for t+1 (land during next iteration's MFMA block)
    if (has_next){
#pragma unroll
      for (int i = 0; i < 8; ++i){
        int js = __shfl(svn, i * 2 + half, 64);
        int jd = __shfl(dvn, i * 2 + half, 64);
        kr[i] = *(const bf4*)(Kb + (size_t)js * DM + l32 * 4);
        qr[i] = *(const bf4*)(Qb + (size_t)jd * DM + l32 * 4);
      }
    }
    sv = svn; dv = dvn; slotv = slotn;
    t = tn;
  }
}

// ---------------- K2c: per-node gather reduction (32 lanes/node, 8-wide rounds) ----------------
__global__ __launch_bounds__(256) void k_gather(const int* __restrict__ off,
    const int* __restrict__ cend, const int* __restrict__ sSrc, const float* __restrict__ sS,
    const __bf16* __restrict__ Vb, __bf16* __restrict__ hattn, int N)
{
  int lane = threadIdx.x & 63;
  int half = lane >> 5, l32 = lane & 31;
  int node = blockIdx.x * 8 + (threadIdx.x >> 6) * 2 + half;
  if (node >= N) return;
  int start = off[node], end = cend[node];
  int hh = l32 >> 2;
  float a0 = 0.f, a1 = 0.f, a2 = 0.f, a3 = 0.f, z = 0.f;
  for (int base = start; base < end; base += 8){
    int idx[8], sj[8]; float s[8];
#pragma unroll
    for (int q = 0; q < 8; ++q) idx[q] = min(base + q, end - 1);
#pragma unroll
    for (int q = 0; q < 8; ++q) sj[q] = sSrc[idx[q]];
#pragma unroll
    for (int q = 0; q < 8; ++q) s[q] = (base + q < end) ? sS[(size_t)idx[q] * NH + hh] : 0.f;
#pragma unroll
    for (int q = 0; q < 8; ++q){
      bf4 v = *(const bf4*)(Vb + (size_t)sj[q] * DM + l32 * 4);
      a0 += s[q] * (float)v[0]; a1 += s[q] * (float)v[1];
      a2 += s[q] * (float)v[2]; a3 += s[q] * (float)v[3];
      z += s[q];
    }
  }
  float invz = 1.f / (z + 1e-6f);
  bf4 o;
  o[0] = (__bf16)(a0 * invz); o[1] = (__bf16)(a1 * invz);
  o[2] = (__bf16)(a2 * invz); o[3] = (__bf16)(a3 * invz);
  *(bf4*)(hattn + (size_t)node * DM + l32 * 4) = o;
}

// ---------------- K3: h2 = h + h_attn @ Wo + bo  (bf16 out) + fused BN1 stats ----------------
__global__ __launch_bounds__(256) void k_attnout(const __bf16* __restrict__ hattn,
    const float* __restrict__ h,
    const __bf16* __restrict__ WoT, const float* __restrict__ bo,
    __bf16* __restrict__ h2, float* __restrict__ s1, float* __restrict__ s2, int N)
{
  __shared__ float ls[256];     // [0..127]=sum, [128..255]=sumsq
  int tid = threadIdx.x;
  ls[tid] = 0.f;
  __syncthreads();
  int lane = tid & 63;
  int r0 = (blockIdx.x * 4 + (tid >> 6)) * 16;
  bool active = (r0 + 16 <= N);
  int r0c = active ? r0 : 0;
  int arow = r0c + (lane & 15);
  int kof = (lane >> 4) << 3;
  bf8 a[4];
#pragma unroll
  for (int kt = 0; kt < 4; ++kt)
    a[kt] = *(const bf8*)(hattn + (size_t)arow * DM + kt * 32 + kof);
  int crow = r0c + ((lane >> 4) << 2);
  int ccol = lane & 15;
#pragma unroll
  for (int nt = 0; nt < 8; ++nt){
    f4 acc = {0.f, 0.f, 0.f, 0.f};
#pragma unroll
    for (int kt = 0; kt < 4; ++kt)
      acc = mfma16(a[kt], bfragT(WoT + (size_t)(nt * 16) * DM + kt * 32, DM, lane), acc);
    int col = nt * 16 + ccol;
    float bb = bo[col];
    if (active){
      float p1 = 0.f, p2 = 0.f;
#pragma unroll
      for (int r = 0; r < 4; ++r){
        size_t idx = (size_t)(crow + r) * DM + col;
        float v = h[idx] + acc[r] + bb;
        h2[idx] = (__bf16)v;
        p1 += v; p2 += v * v;
      }
      atomicAdd(&ls[col], p1);
      atomicAdd(&ls[128 + col], p2);
    }
  }
  __syncthreads();
  if (tid < 128){
    atomicAdd(&s1[tid], ls[tid]);
    atomicAdd(&s2[tid], ls[128 + tid]);
  }
}

__global__ void k_bncoef(const float* __restrict__ s1, const float* __restrict__ s2,
    const float* __restrict__ gam, const float* __restrict__ bet,
    float* __restrict__ cs, float* __restrict__ cb, int N)
{
  int c = threadIdx.x;
  if (c >= DM) return;
  float mean = s1[c] / (float)N;
  float var  = s2[c] / (float)N - mean * mean;
  float rs   = rsqrtf(var + 1e-5f);
  float sc   = gam[c] * rs;
  cs[c] = sc;
  cb[c] = bet[c] - mean * sc;
}

__global__ void k_bnapply(float* __restrict__ t, const float* __restrict__ cs,
    const float* __restrict__ cb, long long total4)
{
  long long i = (long long)blockIdx.x * blockDim.x + threadIdx.x;
  if (i >= total4) return;
  f4* p = (f4*)t + i;
  f4 v = *p;
  int c = (int)((i * 4) & (DM - 1));
  v[0] = v[0] * cs[c]     + cb[c];
  v[1] = v[1] * cs[c + 1] + cb[c + 1];
  v[2] = v[2] * cs[c + 2] + cb[c + 2];
  v[3] = v[3] * cs[c + 3] + cb[c + 3];
  *p = v;
}

// ---------------- K6: FFN fused (x=BN1(h2); t = x + relu(x@W1+b1)@W2 + b2) + BN2 stats ----------------
__global__ __launch_bounds__(256) void k_ffn(const __bf16* __restrict__ h2,
    const float* __restrict__ c1s, const float* __restrict__ c1b,
    const __bf16* __restrict__ W1T, const float* __restrict__ b1,
    const __bf16* __restrict__ W2T, const float* __restrict__ b2,
    float* __restrict__ t, float* __restrict__ s1, float* __restrict__ s2, int N)
{
  __shared__ __bf16 hid[4][16][256];   // 32 KiB
  __shared__ float ls[256];
  int tid = threadIdx.x;
  ls[tid] = 0.f;
  int lane = tid & 63, wave = tid >> 6;
  int r0 = (blockIdx.x * 4 + wave) * 16;
  bool active = (r0 + 16 <= N);
  int r0c = active ? r0 : 0;

  int arow = r0c + (lane & 15);
  int kof = (lane >> 4) << 3;
  bf8 a[4];
#pragma unroll
  for (int kt = 0; kt < 4; ++kt){
    int kb = kt * 32 + kof;
    bf8 hv = *(const bf8*)(h2 + (size_t)arow * DM + kb);
    const f4* ps = (const f4*)(c1s + kb);
    const f4* pb = (const f4*)(c1b + kb);
    f4 s0 = ps[0], s1v = ps[1], b0 = pb[0], b1v = pb[1];
    bf8 r;
    r[0]=(__bf16)((float)hv[0]*s0[0]+b0[0]); r[1]=(__bf16)((float)hv[1]*s0[1]+b0[1]);
    r[2]=(__bf16)((float)hv[2]*s0[2]+b0[2]); r[3]=(__bf16)((float)hv[3]*s0[3]+b0[3]);
    r[4]=(__bf16)((float)hv[4]*s1v[0]+b1v[0]); r[5]=(__bf16)((float)hv[5]*s1v[1]+b1v[1]);
    r[6]=(__bf16)((float)hv[6]*s1v[2]+b1v[2]); r[7]=(__bf16)((float)hv[7]*s1v[3]+b1v[3]);
    a[kt] = r;
  }
  int lr = (lane >> 4) << 2;
  int ccol = lane & 15;
  // GEMM1: 16x256, relu -> LDS (bf16)
#pragma unroll
  for (int nt = 0; nt < 16; ++nt){
    f4 acc = {0.f, 0.f, 0.f, 0.f};
#pragma unroll
    for (int kt = 0; kt < 4; ++kt)
      acc = mfma16(a[kt], bfragT(W1T + (size_t)(nt * 16) * DM + kt * 32, DM, lane), acc);
    int col = nt * 16 + ccol;
    float bb = b1[col];
#pragma unroll
    for (int r = 0; r < 4; ++r)
      hid[wave][lr + r][col] = (__bf16)fmaxf(acc[r] + bb, 0.f);
  }
  __syncthreads();
  // GEMM2: 16x128, K=256
  f4 acc2[8];
#pragma unroll
  for (int nt = 0; nt < 8; ++nt){ acc2[nt][0]=0.f; acc2[nt][1]=0.f; acc2[nt][2]=0.f; acc2[nt][3]=0.f; }
#pragma unroll
  for (int kt = 0; kt < 8; ++kt){
    bf8 a2 = *(const bf8*)&hid[wave][lane & 15][kt * 32 + kof];
#pragma unroll
    for (int nt = 0; nt < 8; ++nt)
      acc2[nt] = mfma16(a2, bfragT(W2T + (size_t)(nt * 16) * 256 + kt * 32, 256, lane), acc2[nt]);
  }
  int crow = r0c + lr;
#pragma unroll
  for (int nt = 0; nt < 8; ++nt){
    int col = nt * 16 + ccol;
    float bb = b2[col], sc = c1s[col], sb = c1b[col];
    if (active){
      float p1 = 0.f, p2 = 0.f;
#pragma unroll
      for (int r = 0; r < 4; ++r){
        size_t idx = (size_t)(crow + r) * DM + col;
        float xres = (float)h2[idx] * sc + sb;
        float v = acc2[nt][r] + bb + xres;
        t[idx] = v;
        p1 += v; p2 += v * v;
      }
      atomicAdd(&ls[col], p1);
      atomicAdd(&ls[128 + col], p2);
    }
  }
  __syncthreads();
  if (tid < 128){
    atomicAdd(&s1[tid], ls[tid]);
    atomicAdd(&s2[tid], ls[128 + tid]);
  }
}

// ---------------- host ----------------
extern "C" void kernel_launch(void* const* d_in, const int* in_sizes, int n_in,
                              void* d_out, int out_size, void* d_ws, size_t ws_size,
                              hipStream_t stream)
{
  const float* h    = (const float*)d_in[0];
  const float* e    = (const float*)d_in[2];
  const float* Wq   = (const float*)d_in[3];
  const float* Wk   = (const float*)d_in[4];
  const float* We   = (const float*)d_in[5];
  const float* Wv   = (const float*)d_in[6];
  const float* Wo   = (const float*)d_in[7];
  const float* bo   = (const float*)d_in[8];
  const float* bn1g = (const float*)d_in[9];
  const float* bn1b = (const float*)d_in[10];
  const float* bn2g = (const float*)d_in[11];
  const float* bn2b = (const float*)d_in[12];
  const float* W1   = (const float*)d_in[13];
  const float* b1   = (const float*)d_in[14];
  const float* W2   = (const float*)d_in[15];
  const float* b2   = (const float*)d_in[16];
  const int*   src  = (const int*)d_in[17];
  const int*   dst  = (const int*)d_in[18];

  int N = in_sizes[0] / DM;
  int E = in_sizes[2] / DM;
  float* out = (float*)d_out;

  char* ws = (char*)d_ws;
  size_t off_b = 0;
  auto alloc = [&](size_t bytes) -> char* {
    char* r = ws + off_b;
    off_b += (bytes + 255) & ~(size_t)255;
    return r;
  };
  __bf16* Qb    = (__bf16*)alloc((size_t)N * DM * 2);
  __bf16* Kb    = (__bf16*)alloc((size_t)N * DM * 2);
  __bf16* Vb    = (__bf16*)alloc((size_t)N * DM * 2);
  __bf16* hattn = (__bf16*)alloc((size_t)N * DM * 2);
  __bf16* h2    = (__bf16*)alloc((size_t)N * DM * 2);
  int*   deg    = (int*)alloc((size_t)N * 4);
  int*   offs   = (int*)alloc((size_t)N * 4);
  int*   cursor = (int*)alloc((size_t)N * 4);
  int*   sSrc   = (int*)alloc((size_t)E * 4);
  float* sS     = (float*)alloc((size_t)E * NH * 4);
  float* stats = (float*)alloc(1024 * 4);   // s1a s2a s1b s2b c1s c1b c2s c2b
  float* s1a = stats, *s2a = stats + 128, *s1b = stats + 256, *s2b = stats + 384;
  float* c1s = stats + 512, *c1b = stats + 640, *c2s = stats + 768, *c2b = stats + 896;
  __bf16* WqT = (__bf16*)alloc(16384 * 2);
  __bf16* WkT = (__bf16*)alloc(16384 * 2);
  __bf16* WvT = (__bf16*)alloc(16384 * 2);
  __bf16* WeT = (__bf16*)alloc(16384 * 2);
  __bf16* WoT = (__bf16*)alloc(16384 * 2);
  __bf16* W1T = (__bf16*)alloc(32768 * 2);
  __bf16* W2T = (__bf16*)alloc(32768 * 2);

  hipMemsetAsync(deg, 0, (size_t)N * 4, stream);
  hipMemsetAsync(stats, 0, 512 * 4, stream);

  k_prep<<<576, 256, 0, stream>>>(Wq, Wk, Wv, We, Wo, W1, W2,
                                  WqT, WkT, WvT, WeT, WoT, W1T, W2T);
  k_hist<<<(E + 255) / 256, 256, 0, stream>>>(dst, deg, E);
  k_scan<<<1, 1024, 0, stream>>>(deg, offs, cursor, N);

  int rowblocks = (N / 16 + 3) / 4;
  k_qkv<<<rowblocks, 256, 0, stream>>>(h, WqT, WkT, WvT, Qb, Kb, Vb, N);
  int T = (E + 15) / 16;
  int eblocks = 2048;
  int NW = eblocks * 4;
  k_edge<<<eblocks, 256, 0, stream>>>(e, WeT, Qb, Kb, src, dst, cursor, sSrc, sS, E, T, NW);
  k_gather<<<(N + 7) / 8, 256, 0, stream>>>(offs, cursor, sSrc, sS, Vb, hattn, N);
  k_attnout<<<rowblocks, 256, 0, stream>>>(hattn, h, WoT, bo, h2, s1a, s2a, N);
  k_bncoef<<<1, 128, 0, stream>>>(s1a, s2a, bn1g, bn1b, c1s, c1b, N);
  k_ffn<<<rowblocks, 256, 0, stream>>>(h2, c1s, c1b, W1T, b1, W2T, b2, out, s1b, s2b, N);
  k_bncoef<<<1, 128, 0, stream>>>(s1b, s2b, bn2g, bn2b, c2s, c2b, N);
  long long total4 = (long long)N * DM / 4;
  k_bnapply<<<(int)((total4 + 255) / 256), 256, 0, stream>>>(out, c2s, c2b, total4);
}